// Round 9
// baseline (172.622 us; speedup 1.0000x reference)
//
#include <hip/hip_runtime.h>

typedef _Float16 h2 __attribute__((ext_vector_type(2)));
typedef _Float16 h8 __attribute__((ext_vector_type(8)));
typedef float f32x4 __attribute__((ext_vector_type(4)));
typedef float f2 __attribute__((ext_vector_type(2)));

#define B_  16
#define Q_  1024
#define C_  256
#define HW_ 1024
#define TQ  16
#define NTA 512
#define QLD 264    // q_lds leading dim (halfwords): 256 + 8 pad
#define BT  256    // conv kernel threads
#define IPB 4      // images per conv block
#define XR  40     // ximg padded row (halfwords)

__device__ __forceinline__ h2 u2h(unsigned u) { return __builtin_bit_cast(h2, u); }
__device__ __forceinline__ unsigned h2u(h2 h) { return __builtin_bit_cast(unsigned, h); }

// ---------- prepass 1: keys f32 -> f16 ----------
__global__ void cvt_keys_f16(const float* __restrict__ src,
                             _Float16* __restrict__ dst, int n8) {
    int i = blockIdx.x * blockDim.x + threadIdx.x;
    if (i >= n8) return;
    const float4* s = (const float4*)src;
    float4 a = s[2 * i], b = s[2 * i + 1];
    h8 v;
    v[0] = (_Float16)a.x; v[1] = (_Float16)a.y; v[2] = (_Float16)a.z; v[3] = (_Float16)a.w;
    v[4] = (_Float16)b.x; v[5] = (_Float16)b.y; v[6] = (_Float16)b.z; v[7] = (_Float16)b.w;
    *(h8*)(dst + (size_t)i * 8) = v;
}

// ---------- prepass 2: pack conv weights as f32 channel-pairs ----------
// wpkf (f32): [0..71]   w1p[t][p] = (w1[2p][t], w1[2p+1][t])  at (t*4+p)*2
//             [72..79]  b1p[p]    = (b1[2p], b1[2p+1])        at 72+2p
//             [80..151] w2p[t][p] = (w2[2p][t], w2[2p+1][t])  at 80+(t*4+p)*2
//             [152]     b2
__global__ void pack_weights(const float* __restrict__ w1, const float* __restrict__ b1,
                             const float* __restrict__ w2, const float* __restrict__ b2,
                             float* __restrict__ wpkf) {
    int t = threadIdx.x;
    if (t < 36) {
        int tt = t >> 2, p = t & 3;
        wpkf[2 * t + 0] = w1[(2 * p) * 9 + tt];
        wpkf[2 * t + 1] = w1[(2 * p + 1) * 9 + tt];
    } else if (t < 40) {
        int p = t - 36;
        wpkf[72 + 2 * p + 0] = b1[2 * p];
        wpkf[72 + 2 * p + 1] = b1[2 * p + 1];
    } else if (t < 76) {
        int i = t - 40; int tt = i >> 2, p = i & 3;
        wpkf[80 + 2 * i + 0] = w2[(2 * p) * 9 + tt];
        wpkf[80 + 2 * i + 1] = w2[(2 * p + 1) * 9 + tt];
    } else if (t == 76) {
        wpkf[152] = b2[0];
    }
}

// ---------- kernel A: QK^T (f16 MFMA) + bias + softmax -> xmapg ----------
__global__ __launch_bounds__(NTA, 4) void attn_kernel(
    const float* __restrict__ queries, const _Float16* __restrict__ keysh,
    const int* __restrict__ pos, const float* __restrict__ rel_bias,
    _Float16* __restrict__ xmapg)
{
    __shared__ _Float16 q_lds[TQ * QLD];
    __shared__ _Float16 bias_lds[63 * 64];
    __shared__ float red_max[8][TQ];
    __shared__ float red_sum[8][TQ];
    __shared__ int2  pos_lds[TQ];

    const int tid = threadIdx.x;
    const int bid = blockIdx.x;
    const int swz = (bid & 7) * 128 + (bid >> 3);
    const int batch = swz >> 6;
    const int tile  = swz & 63;

    {
        const float4* qsrc = (const float4*)(queries + (size_t)(batch * Q_ + tile * TQ) * C_);
        #pragma unroll
        for (int i = 0; i < 2; ++i) {
            int e4 = i * NTA + tid;
            float4 v = qsrc[e4];
            int row = e4 >> 6, col4 = e4 & 63;
            _Float16* d = &q_lds[row * QLD + col4 * 4];
            d[0] = (_Float16)v.x; d[1] = (_Float16)v.y;
            d[2] = (_Float16)v.z; d[3] = (_Float16)v.w;
        }
        for (int idx = tid; idx < 63 * 63; idx += NTA) {
            int r = idx / 63;
            bias_lds[r * 64 + (idx - r * 63)] = (_Float16)rel_bias[idx];
        }
        if (tid < TQ)
            pos_lds[tid] = ((const int2*)pos)[batch * Q_ + tile * TQ + tid];
    }
    __syncthreads();

    const int lane = tid & 63;
    const int wv   = tid >> 6;
    const int kgrp = (lane >> 4) * 8;
    const int arow = lane & 15;
    const int rowbase = (lane >> 4) << 2;

    f32x4 acc[8];
    #pragma unroll
    for (int f = 0; f < 8; ++f) acc[f] = f32x4{0.f, 0.f, 0.f, 0.f};

    const _Float16* kb = keysh + (size_t)batch * (HW_ * C_)
                       + (size_t)(wv * 128 + (lane & 15)) * C_ + kgrp;
    #pragma unroll
    for (int ks = 0; ks < 8; ++ks) {
        h8 a = *(const h8*)&q_lds[arow * QLD + ks * 32 + kgrp];
        #pragma unroll
        for (int f = 0; f < 8; ++f) {
            h8 bfr = *(const h8*)(kb + f * (16 * C_) + ks * 32);
            acc[f] = __builtin_amdgcn_mfma_f32_16x16x32_f16(a, bfr, acc[f], 0, 0, 0);
        }
    }

    int p0r[4], p1r[4];
    #pragma unroll
    for (int r = 0; r < 4; ++r) {
        int2 pp = pos_lds[rowbase + r];
        p0r[r] = pp.x; p1r[r] = pp.y;
    }
    float mrow[4] = {-3e38f, -3e38f, -3e38f, -3e38f};
    #pragma unroll
    for (int f = 0; f < 8; ++f) {
        int col = wv * 128 + f * 16 + (lane & 15);
        int hh = col >> 5, ww = col & 31;
        #pragma unroll
        for (int r = 0; r < 4; ++r) {
            float s = acc[f][r] * 0.0625f
                    + (float)bias_lds[(hh - p0r[r] + 31) * 64 + (ww - p1r[r] + 31)];
            acc[f][r] = s;
            mrow[r] = fmaxf(mrow[r], s);
        }
    }
    #pragma unroll
    for (int r = 0; r < 4; ++r) {
        mrow[r] = fmaxf(mrow[r], __shfl_xor(mrow[r], 1, 64));
        mrow[r] = fmaxf(mrow[r], __shfl_xor(mrow[r], 2, 64));
        mrow[r] = fmaxf(mrow[r], __shfl_xor(mrow[r], 4, 64));
        mrow[r] = fmaxf(mrow[r], __shfl_xor(mrow[r], 8, 64));
    }
    if ((lane & 15) == 0) {
        #pragma unroll
        for (int r = 0; r < 4; ++r) red_max[wv][rowbase + r] = mrow[r];
    }
    __syncthreads();

    float M4[4];
    #pragma unroll
    for (int r = 0; r < 4; ++r) {
        float m = red_max[0][rowbase + r];
        #pragma unroll
        for (int w = 1; w < 8; ++w) m = fmaxf(m, red_max[w][rowbase + r]);
        M4[r] = m;
    }
    float sm[4] = {0.f, 0.f, 0.f, 0.f};
    #pragma unroll
    for (int f = 0; f < 8; ++f) {
        #pragma unroll
        for (int r = 0; r < 4; ++r) {
            float e = __expf(acc[f][r] - M4[r]);
            acc[f][r] = e;
            sm[r] += e;
        }
    }
    #pragma unroll
    for (int r = 0; r < 4; ++r) {
        sm[r] += __shfl_xor(sm[r], 1, 64);
        sm[r] += __shfl_xor(sm[r], 2, 64);
        sm[r] += __shfl_xor(sm[r], 4, 64);
        sm[r] += __shfl_xor(sm[r], 8, 64);
    }
    if ((lane & 15) == 0) {
        #pragma unroll
        for (int r = 0; r < 4; ++r) red_sum[wv][rowbase + r] = sm[r];
    }
    __syncthreads();

    float sinv[4];
    #pragma unroll
    for (int r = 0; r < 4; ++r) {
        float S = red_sum[0][rowbase + r];
        #pragma unroll
        for (int w = 1; w < 8; ++w) S += red_sum[w][rowbase + r];
        sinv[r] = 1.0f / S;
    }
    _Float16* xg = xmapg + (size_t)(batch * Q_ + tile * TQ) * HW_;
    #pragma unroll
    for (int f = 0; f < 8; ++f) {
        int col = wv * 128 + f * 16 + (lane & 15);
        #pragma unroll
        for (int r = 0; r < 4; ++r)
            xg[(size_t)(rowbase + r) * HW_ + col] = (_Float16)(acc[f][r] * sinv[r]);
    }
}

// ---------- kernel B: conv1/relu/conv2 + residual (R5 structure, f32 math) ----------
__global__ __launch_bounds__(BT, 2) void conv_kernel(
    const _Float16* __restrict__ xmapg, const float* __restrict__ wpkf,
    float* __restrict__ out)
{
    __shared__ _Float16 ximg[IPB][32 * XR];          // 10240 B
    __shared__ __align__(16) char Hb[16384];         // 1 image H (f16, permuted cols)
    __shared__ float wsh[80];                        // conv1 weights via LDS -> VGPR

    const int tid = threadIdx.x;
    const int bid = blockIdx.x;
    const int swz = (bid & 7) * 512 + (bid >> 3);    // XCD-chunked (4096 % 8 == 0)
    const size_t img0 = (size_t)swz * IPB;

    // ---- stage conv1 weights + 4 images ----
    if (tid < 80) wsh[tid] = wpkf[tid];
    #pragma unroll
    for (int i = 0; i < 2; ++i) {
        int c = i * BT + tid;            // 0..511 : 16B chunks
        int im = c >> 7, cc = c & 127;
        uint4 v = *(const uint4*)(xmapg + img0 * HW_ + (size_t)im * HW_ + cc * 8);
        *(uint4*)&ximg[im][(cc >> 2) * XR + (cc & 3) * 8] = v;
    }
    __syncthreads();

    // ---- conv1 weights: LDS -> VGPR pairs (resident; lb(,2) gives budget) ----
    f2 w1v[9][4], b1v[4];
    #pragma unroll
    for (int t = 0; t < 9; ++t)
        #pragma unroll
        for (int p = 0; p < 4; ++p)
            w1v[t][p] = f2{wsh[(t * 4 + p) * 2], wsh[(t * 4 + p) * 2 + 1]};
    #pragma unroll
    for (int p = 0; p < 4; ++p)
        b1v[p] = f2{wsh[72 + 2 * p], wsh[72 + 2 * p + 1]};
    // ---- conv2 weights: uniform loads (scalarized to SGPR) ----
    f2 w2u[9][4];
    #pragma unroll
    for (int t = 0; t < 9; ++t)
        #pragma unroll
        for (int p = 0; p < 4; ++p)
            w2u[t][p] = f2{wpkf[80 + (t * 4 + p) * 2], wpkf[80 + (t * 4 + p) * 2 + 1]};
    const float b2r = wpkf[152];

    // thread -> (y, 4-px x-run)
    const int x0 = (tid & 7) << 2;
    const int y  = tid >> 3;

    #pragma unroll 1
    for (int img = 0; img < IPB; ++img) {
        const _Float16* xim = &ximg[img][0];

        // --- gather x neighborhood, convert ONCE to f32: xf[dy][0..5] = v_{-1}..v_4 ---
        float xf[3][6];
        #pragma unroll
        for (int dy = 0; dy < 3; ++dy) {
            int yy = y + dy - 1;
            unsigned b0 = 0, b1w = 0, em = 0, e4 = 0;
            if ((unsigned)yy < 32u) {
                const _Float16* row = xim + yy * XR + x0;
                uint2 bb = *(const uint2*)row;        // (v0,v1 | v2,v3)
                b0 = bb.x; b1w = bb.y;
                if (x0 > 0)      em = *(const unsigned short*)(row - 1);  // v-1
                if (x0 + 4 < 32) e4 = *(const unsigned short*)(row + 4);  // v4
            }
            xf[dy][0] = (float)u2h(em)[0];
            xf[dy][1] = (float)u2h(b0)[0];
            xf[dy][2] = (float)u2h(b0)[1];
            xf[dy][3] = (float)u2h(b1w)[0];
            xf[dy][4] = (float)u2h(b1w)[1];
            xf[dy][5] = (float)u2h(e4)[0];
        }

        // --- conv1: f32 channel-pair accumulation (v_pk_fma_f32 target) ---
        f2 acc1[4][4];
        #pragma unroll
        for (int j = 0; j < 4; ++j)
            #pragma unroll
            for (int p = 0; p < 4; ++p) acc1[j][p] = b1v[p];
        #pragma unroll
        for (int dy = 0; dy < 3; ++dy) {
            #pragma unroll
            for (int dx = 0; dx < 3; ++dx) {
                const int t = dy * 3 + dx;
                #pragma unroll
                for (int j = 0; j < 4; ++j) {
                    const float xv = xf[dy][j + dx];
                    #pragma unroll
                    for (int p = 0; p < 4; ++p)
                        acc1[j][p] += xv * w1v[t][p];
                }
            }
        }

        __syncthreads();   // previous image's conv2 readers done with Hb

        // relu + pack f16 pairs, store (R5 slot permutation: c -> (c&3)*8 + (c>>2))
        {
            char* wbp = Hb + (y << 9);
            const int m4 = x0 >> 2;
            #pragma unroll
            for (int j = 0; j < 4; ++j) {
                uint4 hv;
                #pragma unroll
                for (int p = 0; p < 4; ++p) {
                    h2 r;
                    r[0] = (_Float16)fmaxf(acc1[j][p][0], 0.f);
                    r[1] = (_Float16)fmaxf(acc1[j][p][1], 0.f);
                    ((unsigned*)&hv)[p] = h2u(r);
                }
                *(uint4*)(wbp + ((j * 8 + m4) << 4)) = hv;
            }
        }
        __syncthreads();   // Hb ready

        // --- conv2 + residual -> out (R5 guarded reads; f32 pair accum) ---
        f2 a2v[4];
        #pragma unroll
        for (int j = 0; j < 4; ++j) a2v[j] = f2{0.f, 0.f};
        #pragma unroll
        for (int dy = 0; dy < 3; ++dy) {
            int yy = y + dy - 1;
            uint4 Hv[6];
            if ((unsigned)yy < 32u) {
                const char* rb = Hb + (yy << 9);
                #pragma unroll
                for (int k = 0; k < 6; ++k) {
                    int c = x0 - 1 + k;
                    if ((unsigned)c < 32u) {
                        unsigned g = (((unsigned)(c & 3)) << 3) | ((unsigned)c >> 2);
                        Hv[k] = *(const uint4*)(rb + (g << 4));
                    } else
                        Hv[k] = uint4{0u, 0u, 0u, 0u};
                }
            } else {
                #pragma unroll
                for (int k = 0; k < 6; ++k) Hv[k] = uint4{0u, 0u, 0u, 0u};
            }
            // convert H once per k, reuse across the 3 pixels that touch it
            f2 hf[6][4];
            #pragma unroll
            for (int k = 0; k < 6; ++k) {
                #pragma unroll
                for (int p = 0; p < 4; ++p) {
                    h2 v = u2h(((const unsigned*)&Hv[k])[p]);
                    hf[k][p] = f2{(float)v[0], (float)v[1]};
                }
            }
            #pragma unroll
            for (int dx = 0; dx < 3; ++dx) {
                const int t = dy * 3 + dx;
                #pragma unroll
                for (int j = 0; j < 4; ++j) {
                    #pragma unroll
                    for (int p = 0; p < 4; ++p)
                        a2v[j] += hf[j + dx][p] * w2u[t][p];
                }
            }
        }
        {
            const _Float16* xr4 = xim + y * XR + x0;
            uint2 rr = *(const uint2*)xr4;
            h2 lo = u2h(rr.x), hi = u2h(rr.y);
            float4 o;
            o.x = (float)lo[0] + (a2v[0][0] + a2v[0][1] + b2r);
            o.y = (float)lo[1] + (a2v[1][0] + a2v[1][1] + b2r);
            o.z = (float)hi[0] + (a2v[2][0] + a2v[2][1] + b2r);
            o.w = (float)hi[1] + (a2v[3][0] + a2v[3][1] + b2r);
            *(float4*)(out + (img0 + img) * HW_ + y * 32 + x0) = o;
        }
    }
}

extern "C" void kernel_launch(void* const* d_in, const int* in_sizes, int n_in,
                              void* d_out, int out_size, void* d_ws, size_t ws_size,
                              hipStream_t stream) {
    const float* queries  = (const float*)d_in[0];
    const float* keys     = (const float*)d_in[1];
    const int*   pos      = (const int*)d_in[2];
    const float* rel_bias = (const float*)d_in[3];
    const float* w1       = (const float*)d_in[4];
    const float* b1       = (const float*)d_in[5];
    const float* w2       = (const float*)d_in[6];
    const float* b2       = (const float*)d_in[7];
    float* out = (float*)d_out;

    float*     wpkf  = (float*)d_ws;                                     // 4 KiB slot
    _Float16*  keysh = (_Float16*)((char*)d_ws + 4096);                  // 8 MiB
    _Float16*  xmapg = (_Float16*)((char*)d_ws + 4096 + 8388608);        // 32 MiB

    const int n8 = (B_ * HW_ * C_) / 8;  // 524288
    pack_weights<<<dim3(1), dim3(128), 0, stream>>>(w1, b1, w2, b2, wpkf);
    cvt_keys_f16<<<dim3(n8 / 256), dim3(256), 0, stream>>>(keys, keysh, n8);
    attn_kernel<<<dim3(B_ * (Q_ / TQ)), dim3(NTA), 0, stream>>>(
        queries, keysh, pos, rel_bias, xmapg);
    conv_kernel<<<dim3((B_ * Q_) / IPB), dim3(BT), 0, stream>>>(xmapg, wpkf, out);
}

// Round 10
// 138.175 us; speedup vs baseline: 1.2493x; 1.2493x over previous
//
#include <hip/hip_runtime.h>

typedef _Float16 h2 __attribute__((ext_vector_type(2)));
typedef _Float16 h8 __attribute__((ext_vector_type(8)));
typedef float f32x4 __attribute__((ext_vector_type(4)));

#define B_  16
#define Q_  1024
#define C_  256
#define HW_ 1024
#define TQ  16
#define NTA 512
#define QLD 264    // q_lds leading dim (halfwords): 256 + 8 pad
#define BT  256    // conv kernel threads
#define IPB 4      // images per conv block
#define XRB 80     // bytes per padded ximg row (40 halfwords: 32 px + 8 zero pad)
#define XIMGB (34 * XRB)   // padded image: 34 rows (zero top/bottom)
#define HRB 576    // bytes per Hb row (36 slots * 16B, zero border)

__device__ __forceinline__ h2 u2h(unsigned u) { return __builtin_bit_cast(h2, u); }
__device__ __forceinline__ unsigned h2u(h2 h) { return __builtin_bit_cast(unsigned, h); }

// proven-correct packed dot path (R5): f32 acc += dot(h2 x, h2 w)
__device__ __forceinline__ float fdot2f(h2 a, h2 b, float c) {
#if __has_builtin(__builtin_amdgcn_fdot2)
    return __builtin_amdgcn_fdot2(a, b, c, false);
#else
    return c + (float)a[0] * (float)b[0] + (float)a[1] * (float)b[1];
#endif
}
__device__ __forceinline__ float dotw(unsigned x, unsigned w, float acc) {
    return fdot2f(u2h(x), u2h(w), acc);
}

// ---------- prepass 1: keys f32 -> f16 ----------
__global__ void cvt_keys_f16(const float* __restrict__ src,
                             _Float16* __restrict__ dst, int n8) {
    int i = blockIdx.x * blockDim.x + threadIdx.x;
    if (i >= n8) return;
    const float4* s = (const float4*)src;
    float4 a = s[2 * i], b = s[2 * i + 1];
    h8 v;
    v[0] = (_Float16)a.x; v[1] = (_Float16)a.y; v[2] = (_Float16)a.z; v[3] = (_Float16)a.w;
    v[4] = (_Float16)b.x; v[5] = (_Float16)b.y; v[6] = (_Float16)b.z; v[7] = (_Float16)b.w;
    *(h8*)(dst + (size_t)i * 8) = v;
}

// ---------- prepass 2: pack conv weights (R5-proven layout) ----------
// wpk (u32): [0..23] wA[ch][dy]=(w1[ch,dy,0],w1[ch,dy,1])
//            [24..47] wB[ch][dy]=(w1[ch,dy,2],0)
//            [48..55] b1[ch] (f32 bits)
//            [56..91] w2s[t9][c2]=(w2[2c2,t9],w2[2c2+1,t9])
//            [92]     b2 (f32 bits)
__global__ void pack_weights(const float* __restrict__ w1, const float* __restrict__ b1,
                             const float* __restrict__ w2, const float* __restrict__ b2,
                             unsigned* __restrict__ wpk) {
    int t = threadIdx.x;
    if (t < 24) {
        int ch = t / 3, dy = t - ch * 3;
        h2 v = {(_Float16)w1[ch * 9 + dy * 3 + 0], (_Float16)w1[ch * 9 + dy * 3 + 1]};
        wpk[t] = h2u(v);
    } else if (t < 48) {
        int i = t - 24; int ch = i / 3, dy = i - ch * 3;
        h2 v = {(_Float16)w1[ch * 9 + dy * 3 + 2], (_Float16)0.f};
        wpk[t] = h2u(v);
    } else if (t < 56) {
        wpk[t] = __builtin_bit_cast(unsigned, b1[t - 48]);
    } else if (t < 92) {
        int i = t - 56; int t9 = i >> 2, c2 = i & 3;
        h2 v = {(_Float16)w2[(2 * c2) * 9 + t9], (_Float16)w2[(2 * c2 + 1) * 9 + t9]};
        wpk[t] = h2u(v);
    } else if (t == 92) {
        wpk[t] = __builtin_bit_cast(unsigned, b2[0]);
    }
}

// ---------- kernel A: QK^T (f16 MFMA) + bias + softmax -> xmapg (unchanged, proven) ----------
__global__ __launch_bounds__(NTA, 4) void attn_kernel(
    const float* __restrict__ queries, const _Float16* __restrict__ keysh,
    const int* __restrict__ pos, const float* __restrict__ rel_bias,
    _Float16* __restrict__ xmapg)
{
    __shared__ _Float16 q_lds[TQ * QLD];
    __shared__ _Float16 bias_lds[63 * 64];
    __shared__ float red_max[8][TQ];
    __shared__ float red_sum[8][TQ];
    __shared__ int2  pos_lds[TQ];

    const int tid = threadIdx.x;
    const int bid = blockIdx.x;
    const int swz = (bid & 7) * 128 + (bid >> 3);
    const int batch = swz >> 6;
    const int tile  = swz & 63;

    {
        const float4* qsrc = (const float4*)(queries + (size_t)(batch * Q_ + tile * TQ) * C_);
        #pragma unroll
        for (int i = 0; i < 2; ++i) {
            int e4 = i * NTA + tid;
            float4 v = qsrc[e4];
            int row = e4 >> 6, col4 = e4 & 63;
            _Float16* d = &q_lds[row * QLD + col4 * 4];
            d[0] = (_Float16)v.x; d[1] = (_Float16)v.y;
            d[2] = (_Float16)v.z; d[3] = (_Float16)v.w;
        }
        for (int idx = tid; idx < 63 * 63; idx += NTA) {
            int r = idx / 63;
            bias_lds[r * 64 + (idx - r * 63)] = (_Float16)rel_bias[idx];
        }
        if (tid < TQ)
            pos_lds[tid] = ((const int2*)pos)[batch * Q_ + tile * TQ + tid];
    }
    __syncthreads();

    const int lane = tid & 63;
    const int wv   = tid >> 6;
    const int kgrp = (lane >> 4) * 8;
    const int arow = lane & 15;
    const int rowbase = (lane >> 4) << 2;

    f32x4 acc[8];
    #pragma unroll
    for (int f = 0; f < 8; ++f) acc[f] = f32x4{0.f, 0.f, 0.f, 0.f};

    const _Float16* kb = keysh + (size_t)batch * (HW_ * C_)
                       + (size_t)(wv * 128 + (lane & 15)) * C_ + kgrp;
    #pragma unroll
    for (int ks = 0; ks < 8; ++ks) {
        h8 a = *(const h8*)&q_lds[arow * QLD + ks * 32 + kgrp];
        #pragma unroll
        for (int f = 0; f < 8; ++f) {
            h8 bfr = *(const h8*)(kb + f * (16 * C_) + ks * 32);
            acc[f] = __builtin_amdgcn_mfma_f32_16x16x32_f16(a, bfr, acc[f], 0, 0, 0);
        }
    }

    int p0r[4], p1r[4];
    #pragma unroll
    for (int r = 0; r < 4; ++r) {
        int2 pp = pos_lds[rowbase + r];
        p0r[r] = pp.x; p1r[r] = pp.y;
    }
    float mrow[4] = {-3e38f, -3e38f, -3e38f, -3e38f};
    #pragma unroll
    for (int f = 0; f < 8; ++f) {
        int col = wv * 128 + f * 16 + (lane & 15);
        int hh = col >> 5, ww = col & 31;
        #pragma unroll
        for (int r = 0; r < 4; ++r) {
            float s = acc[f][r] * 0.0625f
                    + (float)bias_lds[(hh - p0r[r] + 31) * 64 + (ww - p1r[r] + 31)];
            acc[f][r] = s;
            mrow[r] = fmaxf(mrow[r], s);
        }
    }
    #pragma unroll
    for (int r = 0; r < 4; ++r) {
        mrow[r] = fmaxf(mrow[r], __shfl_xor(mrow[r], 1, 64));
        mrow[r] = fmaxf(mrow[r], __shfl_xor(mrow[r], 2, 64));
        mrow[r] = fmaxf(mrow[r], __shfl_xor(mrow[r], 4, 64));
        mrow[r] = fmaxf(mrow[r], __shfl_xor(mrow[r], 8, 64));
    }
    if ((lane & 15) == 0) {
        #pragma unroll
        for (int r = 0; r < 4; ++r) red_max[wv][rowbase + r] = mrow[r];
    }
    __syncthreads();

    float M4[4];
    #pragma unroll
    for (int r = 0; r < 4; ++r) {
        float m = red_max[0][rowbase + r];
        #pragma unroll
        for (int w = 1; w < 8; ++w) m = fmaxf(m, red_max[w][rowbase + r]);
        M4[r] = m;
    }
    float sm[4] = {0.f, 0.f, 0.f, 0.f};
    #pragma unroll
    for (int f = 0; f < 8; ++f) {
        #pragma unroll
        for (int r = 0; r < 4; ++r) {
            float e = __expf(acc[f][r] - M4[r]);
            acc[f][r] = e;
            sm[r] += e;
        }
    }
    #pragma unroll
    for (int r = 0; r < 4; ++r) {
        sm[r] += __shfl_xor(sm[r], 1, 64);
        sm[r] += __shfl_xor(sm[r], 2, 64);
        sm[r] += __shfl_xor(sm[r], 4, 64);
        sm[r] += __shfl_xor(sm[r], 8, 64);
    }
    if ((lane & 15) == 0) {
        #pragma unroll
        for (int r = 0; r < 4; ++r) red_sum[wv][rowbase + r] = sm[r];
    }
    __syncthreads();

    float sinv[4];
    #pragma unroll
    for (int r = 0; r < 4; ++r) {
        float S = red_sum[0][rowbase + r];
        #pragma unroll
        for (int w = 1; w < 8; ++w) S += red_sum[w][rowbase + r];
        sinv[r] = 1.0f / S;
    }
    _Float16* xg = xmapg + (size_t)(batch * Q_ + tile * TQ) * HW_;
    #pragma unroll
    for (int f = 0; f < 8; ++f) {
        int col = wv * 128 + f * 16 + (lane & 15);
        #pragma unroll
        for (int r = 0; r < 4; ++r)
            xg[(size_t)(rowbase + r) * HW_ + col] = (_Float16)(acc[f][r] * sinv[r]);
    }
}

// ---------- kernel B: conv1/relu/conv2 + residual (padded, guard-free) ----------
__global__ __launch_bounds__(BT, 4) void conv_kernel(
    const _Float16* __restrict__ xmapg, const unsigned* __restrict__ wpk,
    float* __restrict__ out)
{
    __shared__ __align__(16) char xall[16 + IPB * XIMGB];   // 16B guard + 4 padded images (10896 B)
    __shared__ __align__(16) char Hb[34 * HRB];             // bordered H (19584 B)
    __shared__ unsigned wsh[56];                            // conv1 weights via LDS

    const int tid = threadIdx.x;
    const int bid = blockIdx.x;
    const int swz = (bid & 7) * 512 + (bid >> 3);    // XCD-chunked (4096 % 8 == 0)
    const size_t img0 = (size_t)swz * IPB;

    // ---- zero-fill xall (pads/guard) and Hb (border) ----
    {
        const uint4 z = uint4{0u, 0u, 0u, 0u};
        uint4* xz = (uint4*)xall;
        for (int i = tid; i < (int)sizeof(xall) / 16; i += BT) xz[i] = z;
        uint4* hz = (uint4*)Hb;
        for (int i = tid; i < (int)sizeof(Hb) / 16; i += BT) hz[i] = z;
    }
    if (tid < 56) wsh[tid] = wpk[tid];
    __syncthreads();   // zeros visible before interior writes

    // ---- stage 4 images (rows at r+1, cols 0..31 of 40) ----
    #pragma unroll
    for (int i = 0; i < 2; ++i) {
        int c = i * BT + tid;            // 0..511 : 16B chunks
        int im = c >> 7, cc = c & 127, r = cc >> 2, q = cc & 3;
        uint4 v = *(const uint4*)(xmapg + img0 * HW_ + (size_t)im * HW_ + cc * 8);
        *(uint4*)(xall + 16 + im * XIMGB + (r + 1) * XRB + q * 16) = v;
    }

    // ---- conv1 weights: LDS -> VGPR once; conv2 weights: uniform -> SGPR ----
    unsigned wA[8][3], wB[8][3];
    float b1r[8];
    #pragma unroll
    for (int ch = 0; ch < 8; ++ch) {
        b1r[ch] = __builtin_bit_cast(float, wsh[48 + ch]);
        #pragma unroll
        for (int dy = 0; dy < 3; ++dy) {
            wA[ch][dy] = wsh[ch * 3 + dy];
            wB[ch][dy] = wsh[24 + ch * 3 + dy];
        }
    }
    unsigned w2s[9][4];
    #pragma unroll
    for (int t = 0; t < 9; ++t)
        #pragma unroll
        for (int c2 = 0; c2 < 4; ++c2) w2s[t][c2] = wpk[56 + t * 4 + c2];
    const float b2r = __builtin_bit_cast(float, wpk[92]);

    // thread -> (y, 4-px x-run)
    const int m4 = tid & 7;
    const int y  = tid >> 3;
    const int x0 = m4 << 2;

    const char* const xb  = xall + 16 + y * XRB + 2 * x0;   // padded row r'=y (+dy*XRB)
    char* const hwr = Hb + (y + 1) * HRB + m4 * 16;         // conv1 store base
    const char* const hrd = Hb + y * HRB + m4 * 16;         // conv2 read base

    __syncthreads();   // staging complete

    #pragma unroll 1
    for (int img = 0; img < IPB; ++img) {
        const char* xi = xb + img * XIMGB;

        // --- gather: 9 imm-offset reads + 3 alignbit, no guards (zero pads) ---
        unsigned Pm[3], Pc[3], Pe[3], A0[3], A1[3], E4[3];
        #pragma unroll
        for (int dy = 0; dy < 3; ++dy) {
            unsigned pv = *(const unsigned*)(xi + dy * XRB - 4);   // (v-2, v-1)
            uint2 a01   = *(const uint2*)(xi + dy * XRB);          // (v0,v1 | v2,v3)
            unsigned e4 = *(const unsigned*)(xi + dy * XRB + 8);   // (v4, v5)
            A0[dy] = a01.x; A1[dy] = a01.y; E4[dy] = e4;
            Pm[dy] = __builtin_amdgcn_alignbit(a01.x, pv, 16);     // (v-1, v0)
            Pc[dy] = __builtin_amdgcn_alignbit(a01.y, a01.x, 16);  // (v1, v2)
            Pe[dy] = __builtin_amdgcn_alignbit(e4, a01.y, 16);     // (v3, v4)
        }

        // --- conv1: f32 accum via builtin dot2 (R5-proven pairing) ---
        unsigned hvw[4][4];   // [px][chpair]
        #pragma unroll
        for (int p = 0; p < 4; ++p) {
            const int cA = 2 * p, cB = 2 * p + 1;
            float sA[4], sB[4];
            #pragma unroll
            for (int j = 0; j < 4; ++j) { sA[j] = b1r[cA]; sB[j] = b1r[cB]; }
            #pragma unroll
            for (int dy = 0; dy < 3; ++dy) {
                sA[0] = dotw(Pm[dy], wA[cA][dy], sA[0]);
                sA[0] = dotw(Pc[dy], wB[cA][dy], sA[0]);
                sA[1] = dotw(A0[dy], wA[cA][dy], sA[1]);
                sA[1] = dotw(A1[dy], wB[cA][dy], sA[1]);
                sA[2] = dotw(Pc[dy], wA[cA][dy], sA[2]);
                sA[2] = dotw(Pe[dy], wB[cA][dy], sA[2]);
                sA[3] = dotw(A1[dy], wA[cA][dy], sA[3]);
                sA[3] = dotw(E4[dy], wB[cA][dy], sA[3]);
                sB[0] = dotw(Pm[dy], wA[cB][dy], sB[0]);
                sB[0] = dotw(Pc[dy], wB[cB][dy], sB[0]);
                sB[1] = dotw(A0[dy], wA[cB][dy], sB[1]);
                sB[1] = dotw(A1[dy], wB[cB][dy], sB[1]);
                sB[2] = dotw(Pc[dy], wA[cB][dy], sB[2]);
                sB[2] = dotw(Pe[dy], wB[cB][dy], sB[2]);
                sB[3] = dotw(A1[dy], wA[cB][dy], sB[3]);
                sB[3] = dotw(E4[dy], wB[cB][dy], sB[3]);
            }
            #pragma unroll
            for (int j = 0; j < 4; ++j) {
                h2 r;
                r[0] = (_Float16)fmaxf(sA[j], 0.f);
                r[1] = (_Float16)fmaxf(sB[j], 0.f);
                hvw[j][p] = h2u(r);
            }
        }

        __syncthreads();   // previous image's conv2 readers done with Hb

        // store: px c=x0+j -> bordered col cp=c+1 -> slot (cp&3)*9 + (cp>>2)
        {
            *(uint4*)(hwr + 144) = uint4{hvw[0][0], hvw[0][1], hvw[0][2], hvw[0][3]};
            *(uint4*)(hwr + 288) = uint4{hvw[1][0], hvw[1][1], hvw[1][2], hvw[1][3]};
            *(uint4*)(hwr + 432) = uint4{hvw[2][0], hvw[2][1], hvw[2][2], hvw[2][3]};
            *(uint4*)(hwr + 16)  = uint4{hvw[3][0], hvw[3][1], hvw[3][2], hvw[3][3]};
        }
        __syncthreads();   // Hb ready

        // --- conv2 + residual (unguarded imm-offset reads; zero border) ---
        float a2[4] = {b2r, b2r, b2r, b2r};
        #pragma unroll
        for (int dy = 0; dy < 3; ++dy) {
            const char* rb = hrd + dy * HRB;
            uint4 Hv[6];
            Hv[0] = *(const uint4*)(rb + 0);     // c = x0-1
            Hv[1] = *(const uint4*)(rb + 144);   // c = x0
            Hv[2] = *(const uint4*)(rb + 288);   // c = x0+1
            Hv[3] = *(const uint4*)(rb + 432);   // c = x0+2
            Hv[4] = *(const uint4*)(rb + 16);    // c = x0+3
            Hv[5] = *(const uint4*)(rb + 160);   // c = x0+4
            #pragma unroll
            for (int j = 0; j < 4; ++j) {
                #pragma unroll
                for (int dx = 0; dx < 3; ++dx) {
                    const int tt = dy * 3 + dx;
                    const uint4 uu = Hv[j + dx];
                    a2[j] = dotw(uu.x, w2s[tt][0], a2[j]);
                    a2[j] = dotw(uu.y, w2s[tt][1], a2[j]);
                    a2[j] = dotw(uu.z, w2s[tt][2], a2[j]);
                    a2[j] = dotw(uu.w, w2s[tt][3], a2[j]);
                }
            }
        }
        {
            h2 lo = u2h(A0[1]), hi = u2h(A1[1]);   // row y (dy=1) = residual x
            float4 o;
            o.x = (float)lo[0] + a2[0];
            o.y = (float)lo[1] + a2[1];
            o.z = (float)hi[0] + a2[2];
            o.w = (float)hi[1] + a2[3];
            *(float4*)(out + (img0 + img) * HW_ + y * 32 + x0) = o;
        }
    }
}

extern "C" void kernel_launch(void* const* d_in, const int* in_sizes, int n_in,
                              void* d_out, int out_size, void* d_ws, size_t ws_size,
                              hipStream_t stream) {
    const float* queries  = (const float*)d_in[0];
    const float* keys     = (const float*)d_in[1];
    const int*   pos      = (const int*)d_in[2];
    const float* rel_bias = (const float*)d_in[3];
    const float* w1       = (const float*)d_in[4];
    const float* b1       = (const float*)d_in[5];
    const float* w2       = (const float*)d_in[6];
    const float* b2       = (const float*)d_in[7];
    float* out = (float*)d_out;

    unsigned*  wpk   = (unsigned*)d_ws;                                  // 4 KiB slot
    _Float16*  keysh = (_Float16*)((char*)d_ws + 4096);                  // 8 MiB
    _Float16*  xmapg = (_Float16*)((char*)d_ws + 4096 + 8388608);        // 32 MiB

    const int n8 = (B_ * HW_ * C_) / 8;  // 524288
    pack_weights<<<dim3(1), dim3(128), 0, stream>>>(w1, b1, w2, b2, wpk);
    cvt_keys_f16<<<dim3(n8 / 256), dim3(256), 0, stream>>>(keys, keysh, n8);
    attn_kernel<<<dim3(B_ * (Q_ / TQ)), dim3(NTA), 0, stream>>>(
        queries, keysh, pos, rel_bias, xmapg);
    conv_kernel<<<dim3((B_ * Q_) / IPB), dim3(BT), 0, stream>>>(xmapg, wpk, out);
}

// Round 11
// 115.803 us; speedup vs baseline: 1.4907x; 1.1932x over previous
//
#include <hip/hip_runtime.h>

typedef _Float16 h2 __attribute__((ext_vector_type(2)));
typedef _Float16 h8 __attribute__((ext_vector_type(8)));
typedef float f32x4 __attribute__((ext_vector_type(4)));

#define B_  16
#define Q_  1024
#define C_  256
#define HW_ 1024
#define TQA 32     // attn queries per block
#define NTA 512
#define QLD 264    // q_lds leading dim (halfwords): 256 + 8 pad
#define BT  256    // conv kernel threads
#define IPB 4      // images per conv block
#define XRB 80     // bytes per padded ximg row (40 halfwords: 32 px + 8 zero pad)
#define XIMGB (34 * XRB)   // padded image: 34 rows (zero top/bottom)
#define HRB 576    // bytes per Hb row (36 slots * 16B, zero border)

__device__ __forceinline__ h2 u2h(unsigned u) { return __builtin_bit_cast(h2, u); }
__device__ __forceinline__ unsigned h2u(h2 h) { return __builtin_bit_cast(unsigned, h); }

// proven-correct packed dot path (R5): f32 acc += dot(h2 x, h2 w)
__device__ __forceinline__ float fdot2f(h2 a, h2 b, float c) {
#if __has_builtin(__builtin_amdgcn_fdot2)
    return __builtin_amdgcn_fdot2(a, b, c, false);
#else
    return c + (float)a[0] * (float)b[0] + (float)a[1] * (float)b[1];
#endif
}
__device__ __forceinline__ float dotw(unsigned x, unsigned w, float acc) {
    return fdot2f(u2h(x), u2h(w), acc);
}

// ---------- prepass 1: keys f32 -> f16 ----------
__global__ void cvt_keys_f16(const float* __restrict__ src,
                             _Float16* __restrict__ dst, int n8) {
    int i = blockIdx.x * blockDim.x + threadIdx.x;
    if (i >= n8) return;
    const float4* s = (const float4*)src;
    float4 a = s[2 * i], b = s[2 * i + 1];
    h8 v;
    v[0] = (_Float16)a.x; v[1] = (_Float16)a.y; v[2] = (_Float16)a.z; v[3] = (_Float16)a.w;
    v[4] = (_Float16)b.x; v[5] = (_Float16)b.y; v[6] = (_Float16)b.z; v[7] = (_Float16)b.w;
    *(h8*)(dst + (size_t)i * 8) = v;
}

// ---------- prepass 2: pack conv weights (R5-proven layout) ----------
__global__ void pack_weights(const float* __restrict__ w1, const float* __restrict__ b1,
                             const float* __restrict__ w2, const float* __restrict__ b2,
                             unsigned* __restrict__ wpk) {
    int t = threadIdx.x;
    if (t < 24) {
        int ch = t / 3, dy = t - ch * 3;
        h2 v = {(_Float16)w1[ch * 9 + dy * 3 + 0], (_Float16)w1[ch * 9 + dy * 3 + 1]};
        wpk[t] = h2u(v);
    } else if (t < 48) {
        int i = t - 24; int ch = i / 3, dy = i - ch * 3;
        h2 v = {(_Float16)w1[ch * 9 + dy * 3 + 2], (_Float16)0.f};
        wpk[t] = h2u(v);
    } else if (t < 56) {
        wpk[t] = __builtin_bit_cast(unsigned, b1[t - 48]);
    } else if (t < 92) {
        int i = t - 56; int t9 = i >> 2, c2 = i & 3;
        h2 v = {(_Float16)w2[(2 * c2) * 9 + t9], (_Float16)w2[(2 * c2 + 1) * 9 + t9]};
        wpk[t] = h2u(v);
    } else if (t == 92) {
        wpk[t] = __builtin_bit_cast(unsigned, b2[0]);
    }
}

// ---------- kernel A: QK^T (f16 MFMA, TQ=32, 2 MFMA per B-load) + bias + softmax ----------
__global__ __launch_bounds__(NTA, 4) void attn_kernel(
    const float* __restrict__ queries, const _Float16* __restrict__ keysh,
    const int* __restrict__ pos, const float* __restrict__ rel_bias,
    _Float16* __restrict__ xmapg)
{
    __shared__ _Float16 q_lds[TQA * QLD];      // 16.9 KiB
    __shared__ _Float16 bias_lds[63 * 64];     // 8 KiB
    __shared__ float red_max[8][TQA];
    __shared__ float red_sum[8][TQA];
    __shared__ int2  pos_lds[TQA];

    const int tid = threadIdx.x;
    const int bid = blockIdx.x;
    const int swz = (bid & 7) * 64 + (bid >> 3);    // XCD-chunked (512 % 8 == 0)
    const int batch = swz >> 5;
    const int tile  = swz & 31;

    {
        const float4* qsrc = (const float4*)(queries + (size_t)(batch * Q_ + tile * TQA) * C_);
        #pragma unroll
        for (int i = 0; i < 4; ++i) {
            int e4 = i * NTA + tid;                 // 0..2047
            float4 v = qsrc[e4];
            int row = e4 >> 6, col4 = e4 & 63;
            _Float16* d = &q_lds[row * QLD + col4 * 4];
            d[0] = (_Float16)v.x; d[1] = (_Float16)v.y;
            d[2] = (_Float16)v.z; d[3] = (_Float16)v.w;
        }
        for (int idx = tid; idx < 63 * 63; idx += NTA) {
            int r = idx / 63;
            bias_lds[r * 64 + (idx - r * 63)] = (_Float16)rel_bias[idx];
        }
        if (tid < TQA)
            pos_lds[tid] = ((const int2*)pos)[batch * Q_ + tile * TQA + tid];
    }
    __syncthreads();

    const int lane = tid & 63;
    const int wv   = tid >> 6;          // 0..7 -> 128-col slice
    const int kgrp = (lane >> 4) * 8;
    const int l15  = lane & 15;
    const int rowbase = (lane >> 4) << 2;

    f32x4 acc0[8], acc1[8];
    #pragma unroll
    for (int f = 0; f < 8; ++f) {
        acc0[f] = f32x4{0.f, 0.f, 0.f, 0.f};
        acc1[f] = f32x4{0.f, 0.f, 0.f, 0.f};
    }

    const _Float16* kb = keysh + (size_t)batch * (HW_ * C_)
                       + (size_t)(wv * 128 + l15) * C_ + kgrp;
    #pragma unroll
    for (int ks = 0; ks < 8; ++ks) {
        h8 a0 = *(const h8*)&q_lds[l15 * QLD + ks * 32 + kgrp];
        h8 a1 = *(const h8*)&q_lds[(16 + l15) * QLD + ks * 32 + kgrp];
        #pragma unroll
        for (int f = 0; f < 8; ++f) {
            h8 bfr = *(const h8*)(kb + f * (16 * C_) + ks * 32);
            acc0[f] = __builtin_amdgcn_mfma_f32_16x16x32_f16(a0, bfr, acc0[f], 0, 0, 0);
            acc1[f] = __builtin_amdgcn_mfma_f32_16x16x32_f16(a1, bfr, acc1[f], 0, 0, 0);
        }
    }
    // C/D: col = wv*128 + f*16 + l15, row(mt) = mt*16 + rowbase + r

    int p0r[2][4], p1r[2][4];
    #pragma unroll
    for (int mt = 0; mt < 2; ++mt)
        #pragma unroll
        for (int r = 0; r < 4; ++r) {
            int2 pp = pos_lds[mt * 16 + rowbase + r];
            p0r[mt][r] = pp.x; p1r[mt][r] = pp.y;
        }

    float mrow[2][4];
    #pragma unroll
    for (int mt = 0; mt < 2; ++mt)
        #pragma unroll
        for (int r = 0; r < 4; ++r) mrow[mt][r] = -3e38f;

    #pragma unroll
    for (int f = 0; f < 8; ++f) {
        int col = wv * 128 + f * 16 + l15;
        int hh = col >> 5, ww = col & 31;
        #pragma unroll
        for (int r = 0; r < 4; ++r) {
            float s0 = acc0[f][r] * 0.0625f
                     + (float)bias_lds[(hh - p0r[0][r] + 31) * 64 + (ww - p1r[0][r] + 31)];
            acc0[f][r] = s0;
            mrow[0][r] = fmaxf(mrow[0][r], s0);
            float s1 = acc1[f][r] * 0.0625f
                     + (float)bias_lds[(hh - p0r[1][r] + 31) * 64 + (ww - p1r[1][r] + 31)];
            acc1[f][r] = s1;
            mrow[1][r] = fmaxf(mrow[1][r], s1);
        }
    }
    #pragma unroll
    for (int mt = 0; mt < 2; ++mt)
        #pragma unroll
        for (int r = 0; r < 4; ++r) {
            float m = mrow[mt][r];
            m = fmaxf(m, __shfl_xor(m, 1, 64));
            m = fmaxf(m, __shfl_xor(m, 2, 64));
            m = fmaxf(m, __shfl_xor(m, 4, 64));
            m = fmaxf(m, __shfl_xor(m, 8, 64));
            mrow[mt][r] = m;
        }
    if (l15 == 0) {
        #pragma unroll
        for (int mt = 0; mt < 2; ++mt)
            #pragma unroll
            for (int r = 0; r < 4; ++r)
                red_max[wv][mt * 16 + rowbase + r] = mrow[mt][r];
    }
    __syncthreads();

    float M4[2][4];
    #pragma unroll
    for (int mt = 0; mt < 2; ++mt)
        #pragma unroll
        for (int r = 0; r < 4; ++r) {
            float m = red_max[0][mt * 16 + rowbase + r];
            #pragma unroll
            for (int w = 1; w < 8; ++w) m = fmaxf(m, red_max[w][mt * 16 + rowbase + r]);
            M4[mt][r] = m;
        }

    float sm[2][4];
    #pragma unroll
    for (int mt = 0; mt < 2; ++mt)
        #pragma unroll
        for (int r = 0; r < 4; ++r) sm[mt][r] = 0.f;
    #pragma unroll
    for (int f = 0; f < 8; ++f) {
        #pragma unroll
        for (int r = 0; r < 4; ++r) {
            float e0 = __expf(acc0[f][r] - M4[0][r]);
            acc0[f][r] = e0; sm[0][r] += e0;
            float e1 = __expf(acc1[f][r] - M4[1][r]);
            acc1[f][r] = e1; sm[1][r] += e1;
        }
    }
    #pragma unroll
    for (int mt = 0; mt < 2; ++mt)
        #pragma unroll
        for (int r = 0; r < 4; ++r) {
            float s = sm[mt][r];
            s += __shfl_xor(s, 1, 64);
            s += __shfl_xor(s, 2, 64);
            s += __shfl_xor(s, 4, 64);
            s += __shfl_xor(s, 8, 64);
            sm[mt][r] = s;
        }
    if (l15 == 0) {
        #pragma unroll
        for (int mt = 0; mt < 2; ++mt)
            #pragma unroll
            for (int r = 0; r < 4; ++r)
                red_sum[wv][mt * 16 + rowbase + r] = sm[mt][r];
    }
    __syncthreads();

    float sinv[2][4];
    #pragma unroll
    for (int mt = 0; mt < 2; ++mt)
        #pragma unroll
        for (int r = 0; r < 4; ++r) {
            float S = red_sum[0][mt * 16 + rowbase + r];
            #pragma unroll
            for (int w = 1; w < 8; ++w) S += red_sum[w][mt * 16 + rowbase + r];
            sinv[mt][r] = 1.0f / S;
        }

    _Float16* xg = xmapg + (size_t)(batch * Q_ + tile * TQA) * HW_;
    #pragma unroll
    for (int f = 0; f < 8; ++f) {
        int col = wv * 128 + f * 16 + l15;
        #pragma unroll
        for (int r = 0; r < 4; ++r) {
            xg[(size_t)(rowbase + r) * HW_ + col] = (_Float16)(acc0[f][r] * sinv[0][r]);
            xg[(size_t)(16 + rowbase + r) * HW_ + col] = (_Float16)(acc1[f][r] * sinv[1][r]);
        }
    }
}

// ---------- kernel B: conv1/relu/conv2 + residual (R10-proven, unchanged) ----------
__global__ __launch_bounds__(BT, 4) void conv_kernel(
    const _Float16* __restrict__ xmapg, const unsigned* __restrict__ wpk,
    float* __restrict__ out)
{
    __shared__ __align__(16) char xall[16 + IPB * XIMGB];   // 16B guard + 4 padded images
    __shared__ __align__(16) char Hb[34 * HRB];             // bordered H (19584 B)
    __shared__ unsigned wsh[56];

    const int tid = threadIdx.x;
    const int bid = blockIdx.x;
    const int swz = (bid & 7) * 512 + (bid >> 3);    // XCD-chunked (4096 % 8 == 0)
    const size_t img0 = (size_t)swz * IPB;

    {
        const uint4 z = uint4{0u, 0u, 0u, 0u};
        uint4* xz = (uint4*)xall;
        for (int i = tid; i < (int)sizeof(xall) / 16; i += BT) xz[i] = z;
        uint4* hz = (uint4*)Hb;
        for (int i = tid; i < (int)sizeof(Hb) / 16; i += BT) hz[i] = z;
    }
    if (tid < 56) wsh[tid] = wpk[tid];
    __syncthreads();

    #pragma unroll
    for (int i = 0; i < 2; ++i) {
        int c = i * BT + tid;
        int im = c >> 7, cc = c & 127, r = cc >> 2, q = cc & 3;
        uint4 v = *(const uint4*)(xmapg + img0 * HW_ + (size_t)im * HW_ + cc * 8);
        *(uint4*)(xall + 16 + im * XIMGB + (r + 1) * XRB + q * 16) = v;
    }

    unsigned wA[8][3], wB[8][3];
    float b1r[8];
    #pragma unroll
    for (int ch = 0; ch < 8; ++ch) {
        b1r[ch] = __builtin_bit_cast(float, wsh[48 + ch]);
        #pragma unroll
        for (int dy = 0; dy < 3; ++dy) {
            wA[ch][dy] = wsh[ch * 3 + dy];
            wB[ch][dy] = wsh[24 + ch * 3 + dy];
        }
    }
    unsigned w2s[9][4];
    #pragma unroll
    for (int t = 0; t < 9; ++t)
        #pragma unroll
        for (int c2 = 0; c2 < 4; ++c2) w2s[t][c2] = wpk[56 + t * 4 + c2];
    const float b2r = __builtin_bit_cast(float, wpk[92]);

    const int m4 = tid & 7;
    const int y  = tid >> 3;
    const int x0 = m4 << 2;

    const char* const xb  = xall + 16 + y * XRB + 2 * x0;
    char* const hwr = Hb + (y + 1) * HRB + m4 * 16;
    const char* const hrd = Hb + y * HRB + m4 * 16;

    __syncthreads();

    #pragma unroll 1
    for (int img = 0; img < IPB; ++img) {
        const char* xi = xb + img * XIMGB;

        unsigned Pm[3], Pc[3], Pe[3], A0[3], A1[3], E4[3];
        #pragma unroll
        for (int dy = 0; dy < 3; ++dy) {
            unsigned pv = *(const unsigned*)(xi + dy * XRB - 4);
            uint2 a01   = *(const uint2*)(xi + dy * XRB);
            unsigned e4 = *(const unsigned*)(xi + dy * XRB + 8);
            A0[dy] = a01.x; A1[dy] = a01.y; E4[dy] = e4;
            Pm[dy] = __builtin_amdgcn_alignbit(a01.x, pv, 16);
            Pc[dy] = __builtin_amdgcn_alignbit(a01.y, a01.x, 16);
            Pe[dy] = __builtin_amdgcn_alignbit(e4, a01.y, 16);
        }

        unsigned hvw[4][4];
        #pragma unroll
        for (int p = 0; p < 4; ++p) {
            const int cA = 2 * p, cB = 2 * p + 1;
            float sA[4], sB[4];
            #pragma unroll
            for (int j = 0; j < 4; ++j) { sA[j] = b1r[cA]; sB[j] = b1r[cB]; }
            #pragma unroll
            for (int dy = 0; dy < 3; ++dy) {
                sA[0] = dotw(Pm[dy], wA[cA][dy], sA[0]);
                sA[0] = dotw(Pc[dy], wB[cA][dy], sA[0]);
                sA[1] = dotw(A0[dy], wA[cA][dy], sA[1]);
                sA[1] = dotw(A1[dy], wB[cA][dy], sA[1]);
                sA[2] = dotw(Pc[dy], wA[cA][dy], sA[2]);
                sA[2] = dotw(Pe[dy], wB[cA][dy], sA[2]);
                sA[3] = dotw(A1[dy], wA[cA][dy], sA[3]);
                sA[3] = dotw(E4[dy], wB[cA][dy], sA[3]);
                sB[0] = dotw(Pm[dy], wA[cB][dy], sB[0]);
                sB[0] = dotw(Pc[dy], wB[cB][dy], sB[0]);
                sB[1] = dotw(A0[dy], wA[cB][dy], sB[1]);
                sB[1] = dotw(A1[dy], wB[cB][dy], sB[1]);
                sB[2] = dotw(Pc[dy], wA[cB][dy], sB[2]);
                sB[2] = dotw(Pe[dy], wB[cB][dy], sB[2]);
                sB[3] = dotw(A1[dy], wA[cB][dy], sB[3]);
                sB[3] = dotw(E4[dy], wB[cB][dy], sB[3]);
            }
            #pragma unroll
            for (int j = 0; j < 4; ++j) {
                h2 r;
                r[0] = (_Float16)fmaxf(sA[j], 0.f);
                r[1] = (_Float16)fmaxf(sB[j], 0.f);
                hvw[j][p] = h2u(r);
            }
        }

        __syncthreads();

        {
            *(uint4*)(hwr + 144) = uint4{hvw[0][0], hvw[0][1], hvw[0][2], hvw[0][3]};
            *(uint4*)(hwr + 288) = uint4{hvw[1][0], hvw[1][1], hvw[1][2], hvw[1][3]};
            *(uint4*)(hwr + 432) = uint4{hvw[2][0], hvw[2][1], hvw[2][2], hvw[2][3]};
            *(uint4*)(hwr + 16)  = uint4{hvw[3][0], hvw[3][1], hvw[3][2], hvw[3][3]};
        }
        __syncthreads();

        float a2[4] = {b2r, b2r, b2r, b2r};
        #pragma unroll
        for (int dy = 0; dy < 3; ++dy) {
            const char* rb = hrd + dy * HRB;
            uint4 Hv[6];
            Hv[0] = *(const uint4*)(rb + 0);
            Hv[1] = *(const uint4*)(rb + 144);
            Hv[2] = *(const uint4*)(rb + 288);
            Hv[3] = *(const uint4*)(rb + 432);
            Hv[4] = *(const uint4*)(rb + 16);
            Hv[5] = *(const uint4*)(rb + 160);
            #pragma unroll
            for (int j = 0; j < 4; ++j) {
                #pragma unroll
                for (int dx = 0; dx < 3; ++dx) {
                    const int tt = dy * 3 + dx;
                    const uint4 uu = Hv[j + dx];
                    a2[j] = dotw(uu.x, w2s[tt][0], a2[j]);
                    a2[j] = dotw(uu.y, w2s[tt][1], a2[j]);
                    a2[j] = dotw(uu.z, w2s[tt][2], a2[j]);
                    a2[j] = dotw(uu.w, w2s[tt][3], a2[j]);
                }
            }
        }
        {
            h2 lo = u2h(A0[1]), hi = u2h(A1[1]);
            float4 o;
            o.x = (float)lo[0] + a2[0];
            o.y = (float)lo[1] + a2[1];
            o.z = (float)hi[0] + a2[2];
            o.w = (float)hi[1] + a2[3];
            *(float4*)(out + (img0 + img) * HW_ + y * 32 + x0) = o;
        }
    }
}

extern "C" void kernel_launch(void* const* d_in, const int* in_sizes, int n_in,
                              void* d_out, int out_size, void* d_ws, size_t ws_size,
                              hipStream_t stream) {
    const float* queries  = (const float*)d_in[0];
    const float* keys     = (const float*)d_in[1];
    const int*   pos      = (const int*)d_in[2];
    const float* rel_bias = (const float*)d_in[3];
    const float* w1       = (const float*)d_in[4];
    const float* b1       = (const float*)d_in[5];
    const float* w2       = (const float*)d_in[6];
    const float* b2       = (const float*)d_in[7];
    float* out = (float*)d_out;

    unsigned*  wpk   = (unsigned*)d_ws;                                  // 4 KiB slot
    _Float16*  keysh = (_Float16*)((char*)d_ws + 4096);                  // 8 MiB
    _Float16*  xmapg = (_Float16*)((char*)d_ws + 4096 + 8388608);        // 32 MiB

    const int n8 = (B_ * HW_ * C_) / 8;  // 524288
    pack_weights<<<dim3(1), dim3(128), 0, stream>>>(w1, b1, w2, b2, wpk);
    cvt_keys_f16<<<dim3(n8 / 256), dim3(256), 0, stream>>>(keys, keysh, n8);
    attn_kernel<<<dim3(B_ * (Q_ / TQA)), dim3(NTA), 0, stream>>>(
        queries, keysh, pos, rel_bias, xmapg);
    conv_kernel<<<dim3((B_ * Q_) / IPB), dim3(BT), 0, stream>>>(xmapg, wpk, out);
}